// Round 15
// baseline (138.400 us; speedup 1.0000x reference)
//
#include <hip/hip_runtime.h>
#include <hip/hip_bf16.h>

#define D 128
#define BSH 7            // 128 dsts per bin
#define BDST 128
#define NCHK 512         // edge chunks for hscat role
#define CHCAP 3200       // max edges per chunk (E/NCHK = 3125)
#define CAPB 5120        // padded records per bin (mean 4096, +16 sigma)

typedef __attribute__((ext_vector_type(8))) short short8;
typedef __attribute__((ext_vector_type(4))) float f32x4;
typedef __attribute__((ext_vector_type(2))) float f32x2;

__device__ __forceinline__ unsigned short f2bf(float f) {
  unsigned u = __float_as_uint(f);
  unsigned r = (u + 0x7FFFu + ((u >> 16) & 1u)) >> 16;
  return (unsigned short)r;
}

// ---------------- K0: W fp32 -> bf16, + zero bincur ---------------------------
__global__ __launch_bounds__(256) void k_wconv(const float* __restrict__ W,
                                               unsigned short* __restrict__ Wb,
                                               int* __restrict__ bincur, int NB) {
  const int i = blockIdx.x * 256 + threadIdx.x;
  if (i < NB) bincur[i] = 0;
  float4 f = ((const float4*)W)[i];
  ushort4 o;
  o.x = f2bf(f.x); o.y = f2bf(f.y); o.z = f2bf(f.z); o.w = f2bf(f.w);
  ((ushort4*)Wb)[i] = o;
}

// ---------------- K1: combo — blocks [0,NCHK): sorted hscat | rest: lin -------
__global__ __launch_bounds__(256) void k_combo(
    const float* __restrict__ h, const unsigned short* __restrict__ Wb,
    const float* __restrict__ w_fc, const float* __restrict__ emb,
    const float* __restrict__ w_emb, unsigned* __restrict__ zd,
    float* __restrict__ a_src, float* __restrict__ a_dst,
    const int* __restrict__ src, const int* __restrict__ dst,
    int* __restrict__ bincur, unsigned* __restrict__ binrec,
    int n, int E, int NB, int CHSZ) {
  __shared__ unsigned recbuf[CHCAP];
  __shared__ int hl[512], gbase[512], loff[512], lcur[512];
  __shared__ int sh[256];
  __shared__ float sfs[4][16], sfd[4][16];
  const int tid = threadIdx.x;

  if ((int)blockIdx.x < NCHK) {
    // ---- hscat role: hist + reserve + LDS counting sort + coalesced write ----
    const int c = blockIdx.x;
    const int beg = c * CHSZ, end = min(beg + CHSZ, E);
    const int cnt = end - beg;
    for (int i = tid; i < 512; i += 256) { hl[i] = 0; lcur[i] = 0; }
    __syncthreads();
    for (int i = beg + tid; i < end; i += 256) atomicAdd(&hl[dst[i] >> BSH], 1);
    __syncthreads();
    for (int b = tid; b < NB; b += 256) {
      int cb = hl[b];
      gbase[b] = cb > 0 ? atomicAdd(&bincur[b], cb) : 0;
    }
    // exclusive scan over 512 bins (2 per thread)
    int v0 = hl[2 * tid], v1 = hl[2 * tid + 1];
    int s = v0 + v1;
    sh[tid] = s;
    __syncthreads();
    for (int off = 1; off < 256; off <<= 1) {
      int a = (tid >= off) ? sh[tid - off] : 0;
      __syncthreads();
      sh[tid] += a;
      __syncthreads();
    }
    int base = sh[tid] - s;
    loff[2 * tid] = base;
    loff[2 * tid + 1] = base + v0;
    __syncthreads();
    // counting-sort records into LDS by bin
    for (int i = beg + tid; i < end; i += 256) {
      int d = dst[i];
      int b = d >> BSH;
      unsigned r = ((unsigned)src[i] << 16) | (unsigned)d;
      int lp = atomicAdd(&lcur[b], 1);
      recbuf[loff[b] + lp] = r;
    }
    __syncthreads();
    // coalesced write: consecutive lanes -> consecutive global slots per run
    for (int i = tid; i < cnt; i += 256) {
      unsigned r = recbuf[i];
      int b = (int)(r & 0xFFFFu) >> BSH;
      binrec[(size_t)b * CAPB + gbase[b] + (i - loff[b])] = r;
    }
    return;
  }

  // ---- lin role: z = h@W^T (MFMA) + fused s_fc and emb dots ----
  const int lane = tid & 63;
  const int wid = tid >> 6;
  const int m0 = (blockIdx.x - NCHK) * 64 + wid * 16;
  if (m0 >= n) return;
  const int c = lane & 15;
  const int g = lane >> 4;

  int arow = m0 + c;
  if (arow >= n) arow = n - 1;
  const float4* hrow = (const float4*)(h + (size_t)arow * 128);

  short8 afr[4];
#pragma unroll
  for (int s = 0; s < 4; ++s) {
    float4 f0 = hrow[8 * s + 2 * g];
    float4 f1 = hrow[8 * s + 2 * g + 1];
    short8 a;
    a[0] = (short)f2bf(f0.x); a[1] = (short)f2bf(f0.y);
    a[2] = (short)f2bf(f0.z); a[3] = (short)f2bf(f0.w);
    a[4] = (short)f2bf(f1.x); a[5] = (short)f2bf(f1.y);
    a[6] = (short)f2bf(f1.z); a[7] = (short)f2bf(f1.w);
    afr[s] = a;
  }

  f32x4 acc[8];
#pragma unroll
  for (int t = 0; t < 8; ++t) acc[t] = (f32x4){0.f, 0.f, 0.f, 0.f};

#pragma unroll
  for (int s = 0; s < 4; ++s) {
#pragma unroll
    for (int t = 0; t < 8; ++t) {
      short8 b = *(const short8*)(Wb + ((size_t)(t * 16 + c) * 128 + 32 * s + 8 * g));
      acc[t] = __builtin_amdgcn_mfma_f32_16x16x32_bf16(afr[s], b, acc[t], 0, 0, 0);
    }
  }

  float wfs[8], wfd[8];
#pragma unroll
  for (int t = 0; t < 8; ++t) {
    wfs[t] = w_fc[t * 16 + c];
    wfd[t] = w_fc[128 + t * 16 + c];
  }

  const int rbase = m0 + 4 * g;
#pragma unroll
  for (int r = 0; r < 4; ++r) {
    const int row = rbase + r;
    if (row < n) {
#pragma unroll
      for (int tp = 0; tp < 4; ++tp) {
        unsigned dw = ((unsigned)f2bf(acc[tp + 4][r]) << 16) | (unsigned)f2bf(acc[tp][r]);
        zd[(size_t)row * 64 + tp * 16 + c] = dw;
      }
    }
    float ps = 0.f, pd = 0.f;
#pragma unroll
    for (int t = 0; t < 8; ++t) {
      ps += acc[t][r] * wfs[t];
      pd += acc[t][r] * wfd[t];
    }
#pragma unroll
    for (int off = 1; off < 16; off <<= 1) {
      ps += __shfl_xor(ps, off, 64);
      pd += __shfl_xor(pd, off, 64);
    }
    if (c == 0) {
      sfs[wid][4 * g + r] = ps;
      sfd[wid][4 * g + r] = pd;
    }
  }
  __syncthreads();

  const int nloc = lane >> 2;
  const int qc = lane & 3;
  const int node2 = m0 + nloc;
  float es = 0.f, ed = 0.f;
  if (node2 < n) {
    const float4* er = (const float4*)(emb + (size_t)node2 * 128 + qc * 32);
    const float4* wsp = (const float4*)(w_emb + qc * 32);
    const float4* wdp = (const float4*)(w_emb + 128 + qc * 32);
#pragma unroll
    for (int j = 0; j < 8; ++j) {
      float4 e4 = er[j], s4 = wsp[j], d4 = wdp[j];
      es += e4.x * s4.x + e4.y * s4.y + e4.z * s4.z + e4.w * s4.w;
      ed += e4.x * d4.x + e4.y * d4.y + e4.z * d4.z + e4.w * d4.w;
    }
  }
  es += __shfl_xor(es, 1, 64); es += __shfl_xor(es, 2, 64);
  ed += __shfl_xor(ed, 1, 64); ed += __shfl_xor(ed, 2, 64);
  if (qc == 0 && node2 < n) {
    a_src[node2] = es + sfs[wid][nloc];
    a_dst[node2] = ed + sfd[wid][nloc];
  }
}

// ---------------- K2: per-bin counting sort + ew -> packed 4B csr -------------
// in record = (src<<16) | dst ; out record = (src<<16) | f2bf(ew).
__global__ __launch_bounds__(256) void k_build(const unsigned* __restrict__ binrec,
                                               const int* __restrict__ bincur,
                                               const float* __restrict__ a_src,
                                               const float* __restrict__ a_dst,
                                               int2* __restrict__ row2,
                                               unsigned* __restrict__ csrp, int n) {
  __shared__ int hist[BDST], lrow[BDST], cur[BDST];
  __shared__ float adl[BDST];
  const int tid = threadIdx.x, b = blockIdx.x;
  const int cntb = bincur[b];
  const unsigned* rb = binrec + (size_t)b * CAPB;
  const int base = b * CAPB;

  if (tid < BDST) {
    hist[tid] = 0;
    int v = b * BDST + tid;
    adl[tid] = (v < n) ? a_dst[v] : 0.f;
  }
  __syncthreads();
  for (int i = tid; i < cntb; i += 256)
    atomicAdd(&hist[rb[i] & (BDST - 1)], 1);
  __syncthreads();
  if (tid < BDST) lrow[tid] = hist[tid];
  __syncthreads();
  for (int off = 1; off < BDST; off <<= 1) {
    int a = (tid < BDST && tid >= off) ? lrow[tid - off] : 0;
    __syncthreads();
    if (tid < BDST) lrow[tid] += a;
    __syncthreads();
  }
  if (tid < BDST) {
    int e = lrow[tid];
    int s = e - hist[tid];
    cur[tid] = s;
    int v = b * BDST + tid;
    if (v < n) row2[v] = make_int2(base + s, base + e);
  }
  __syncthreads();
  for (int i = tid; i < cntb; i += 256) {
    unsigned r = rb[i];
    int dl = r & (BDST - 1);
    unsigned sv = r >> 16;
    float a = a_src[sv] + adl[dl];
    float e = a > 0.f ? a : 0.01f * a;
    float ew = __expf(e);
    int pos = base + atomicAdd(&cur[dl], 1);
    csrp[pos] = (sv << 16) | (unsigned)f2bf(ew);
  }
}

// ---------------- K3: aggregation — packed 4B records, unroll 8 ---------------
__global__ __launch_bounds__(256) void k_agg(const unsigned* __restrict__ zd,
                                             const int2* __restrict__ row2,
                                             const unsigned* __restrict__ csrp,
                                             float* __restrict__ out, int n) {
  const int lane = threadIdx.x & 63;
  const int grp = lane >> 4;
  const int sub = lane & 15;
  const int v = blockIdx.x * 4 + (threadIdx.x >> 6);
  if (v >= n) return;
  const int2 be = row2[v];
  const int beg = be.x, end = be.y;

  f32x2 acc2[4];
#pragma unroll
  for (int j = 0; j < 4; ++j) acc2[j] = (f32x2){0.f, 0.f};
  float ews = 0.f;

#pragma unroll 8
  for (int i = beg + grp; i < end; i += 4) {
    const unsigned r = csrp[i];
    const float ew = __uint_as_float(r << 16);   // bf16 in low 16 -> f32
    const unsigned u = r >> 16;
    const uint4 zz = ((const uint4*)zd)[(size_t)u * 16 + sub];
    ews += ew;
    const f32x2 ew2 = {ew, ew};
    f32x2 z0 = {__uint_as_float(zz.x << 16), __uint_as_float(zz.x & 0xffff0000u)};
    f32x2 z1 = {__uint_as_float(zz.y << 16), __uint_as_float(zz.y & 0xffff0000u)};
    f32x2 z2 = {__uint_as_float(zz.z << 16), __uint_as_float(zz.z & 0xffff0000u)};
    f32x2 z3 = {__uint_as_float(zz.w << 16), __uint_as_float(zz.w & 0xffff0000u)};
    acc2[0] += ew2 * z0;
    acc2[1] += ew2 * z1;
    acc2[2] += ew2 * z2;
    acc2[3] += ew2 * z3;
  }

#pragma unroll
  for (int off = 16; off <= 32; off <<= 1) {
    ews += __shfl_xor(ews, off, 64);
#pragma unroll
    for (int j = 0; j < 4; ++j) {
      acc2[j][0] += __shfl_xor(acc2[j][0], off, 64);
      acc2[j][1] += __shfl_xor(acc2[j][1], off, 64);
    }
  }

  if (grp == 0) {
    const float inv = (end > beg) ? 1.f / ews : 0.f;
    float4 olo = make_float4(acc2[0][0] * inv, acc2[1][0] * inv, acc2[2][0] * inv, acc2[3][0] * inv);
    float4 ohi = make_float4(acc2[0][1] * inv, acc2[1][1] * inv, acc2[2][1] * inv, acc2[3][1] * inv);
    ((float4*)out)[(size_t)v * 32 + sub] = olo;
    ((float4*)out)[(size_t)v * 32 + 16 + sub] = ohi;
  }
}

extern "C" void kernel_launch(void* const* d_in, const int* in_sizes, int n_in,
                              void* d_out, int out_size, void* d_ws, size_t ws_size,
                              hipStream_t stream) {
  const float* h = (const float*)d_in[0];
  const float* emb = (const float*)d_in[1];
  const float* W = (const float*)d_in[2];
  const float* wfc = (const float*)d_in[3];
  const float* wemb = (const float*)d_in[4];
  const int* src = (const int*)d_in[5];
  const int* dst = (const int*)d_in[6];
  const int n = in_sizes[0] / D;
  const int E = in_sizes[5];
  const int NB = (n + BDST - 1) >> BSH;
  const int CHSZ = (E + NCHK - 1) / NCHK;
  const int NLIN = (n + 63) / 64;

  char* ws = (char*)d_ws;
  size_t off = 0;
  auto alloc = [&](size_t bytes) {
    void* p = ws + off;
    off = (off + bytes + 255) & ~(size_t)255;
    return p;
  };
  unsigned* zd = (unsigned*)alloc((size_t)n * 64 * 4);
  unsigned short* Wb = (unsigned short*)alloc(D * D * 2);
  float* a_src = (float*)alloc((size_t)n * 4);
  float* a_dst = (float*)alloc((size_t)n * 4);
  int* bincur = (int*)alloc((size_t)NB * 4);
  int2* row2 = (int2*)alloc((size_t)n * 8);
  unsigned* binrec = (unsigned*)alloc((size_t)NB * CAPB * 4);
  unsigned* csrp = (unsigned*)alloc((size_t)NB * CAPB * 4);
  (void)off;
  (void)ws_size;

  k_wconv<<<(D * D / 4 + 255) / 256, 256, 0, stream>>>(W, Wb, bincur, NB);
  k_combo<<<NCHK + NLIN, 256, 0, stream>>>(h, Wb, wfc, emb, wemb, zd, a_src, a_dst,
                                           src, dst, bincur, binrec, n, E, NB, CHSZ);
  k_build<<<NB, 256, 0, stream>>>(binrec, bincur, a_src, a_dst, row2, csrp, n);
  k_agg<<<(n + 3) / 4, 256, 0, stream>>>(zd, row2, csrp, (float*)d_out, n);
}

// Round 16
// 124.194 us; speedup vs baseline: 1.1144x; 1.1144x over previous
//
#include <hip/hip_runtime.h>
#include <hip/hip_bf16.h>

#define D 128
#define BSH 7            // 128 dsts per bin
#define BDST 128
#define NCHK 512         // edge chunks for hscat role
#define CHCAP 3200       // max edges per chunk (E/NCHK = 3125)
#define CAPB 5120        // padded records per bin (mean 4096, +16 sigma)

typedef __attribute__((ext_vector_type(8))) short short8;
typedef __attribute__((ext_vector_type(4))) float f32x4;
typedef __attribute__((ext_vector_type(2))) float f32x2;

__device__ __forceinline__ unsigned short f2bf(float f) {
  unsigned u = __float_as_uint(f);
  unsigned r = (u + 0x7FFFu + ((u >> 16) & 1u)) >> 16;
  return (unsigned short)r;
}

// ---------------- K0: W fp32 -> bf16, + zero bincur ---------------------------
__global__ __launch_bounds__(256) void k_wconv(const float* __restrict__ W,
                                               unsigned short* __restrict__ Wb,
                                               int* __restrict__ bincur, int NB) {
  const int i = blockIdx.x * 256 + threadIdx.x;
  if (i < NB) bincur[i] = 0;
  float4 f = ((const float4*)W)[i];
  ushort4 o;
  o.x = f2bf(f.x); o.y = f2bf(f.y); o.z = f2bf(f.z); o.w = f2bf(f.w);
  ((ushort4*)Wb)[i] = o;
}

// ---------------- K1: combo — blocks [0,NCHK): sorted hscat | rest: lin -------
__global__ __launch_bounds__(256) void k_combo(
    const float* __restrict__ h, const unsigned short* __restrict__ Wb,
    const float* __restrict__ w_fc, const float* __restrict__ emb,
    const float* __restrict__ w_emb, unsigned* __restrict__ zd,
    float* __restrict__ a_src, float* __restrict__ a_dst,
    const int* __restrict__ src, const int* __restrict__ dst,
    int* __restrict__ bincur, unsigned* __restrict__ binrec,
    int n, int E, int NB, int CHSZ) {
  __shared__ unsigned recbuf[CHCAP];
  __shared__ int hl[512], gbase[512], loff[512], lcur[512];
  __shared__ int sh[256];
  __shared__ float sfs[4][16], sfd[4][16];
  const int tid = threadIdx.x;

  if ((int)blockIdx.x < NCHK) {
    // ---- hscat role: hist + reserve + LDS counting sort + coalesced write ----
    const int c = blockIdx.x;
    const int beg = c * CHSZ, end = min(beg + CHSZ, E);
    const int cnt = end - beg;
    for (int i = tid; i < 512; i += 256) { hl[i] = 0; lcur[i] = 0; }
    __syncthreads();
    for (int i = beg + tid; i < end; i += 256) atomicAdd(&hl[dst[i] >> BSH], 1);
    __syncthreads();
    for (int b = tid; b < NB; b += 256) {
      int cb = hl[b];
      gbase[b] = cb > 0 ? atomicAdd(&bincur[b], cb) : 0;
    }
    // exclusive scan over 512 bins (2 per thread)
    int v0 = hl[2 * tid], v1 = hl[2 * tid + 1];
    int s = v0 + v1;
    sh[tid] = s;
    __syncthreads();
    for (int off = 1; off < 256; off <<= 1) {
      int a = (tid >= off) ? sh[tid - off] : 0;
      __syncthreads();
      sh[tid] += a;
      __syncthreads();
    }
    int base = sh[tid] - s;
    loff[2 * tid] = base;
    loff[2 * tid + 1] = base + v0;
    __syncthreads();
    // counting-sort records into LDS by bin
    for (int i = beg + tid; i < end; i += 256) {
      int d = dst[i];
      int b = d >> BSH;
      unsigned r = ((unsigned)src[i] << 16) | (unsigned)d;
      int lp = atomicAdd(&lcur[b], 1);
      recbuf[loff[b] + lp] = r;
    }
    __syncthreads();
    // coalesced write: consecutive lanes -> consecutive global slots per run
    for (int i = tid; i < cnt; i += 256) {
      unsigned r = recbuf[i];
      int b = (int)(r & 0xFFFFu) >> BSH;
      binrec[(size_t)b * CAPB + gbase[b] + (i - loff[b])] = r;
    }
    return;
  }

  // ---- lin role: z = h@W^T (MFMA) + fused s_fc and emb dots ----
  const int lane = tid & 63;
  const int wid = tid >> 6;
  const int m0 = (blockIdx.x - NCHK) * 64 + wid * 16;
  if (m0 >= n) return;
  const int c = lane & 15;
  const int g = lane >> 4;

  int arow = m0 + c;
  if (arow >= n) arow = n - 1;
  const float4* hrow = (const float4*)(h + (size_t)arow * 128);

  short8 afr[4];
#pragma unroll
  for (int s = 0; s < 4; ++s) {
    float4 f0 = hrow[8 * s + 2 * g];
    float4 f1 = hrow[8 * s + 2 * g + 1];
    short8 a;
    a[0] = (short)f2bf(f0.x); a[1] = (short)f2bf(f0.y);
    a[2] = (short)f2bf(f0.z); a[3] = (short)f2bf(f0.w);
    a[4] = (short)f2bf(f1.x); a[5] = (short)f2bf(f1.y);
    a[6] = (short)f2bf(f1.z); a[7] = (short)f2bf(f1.w);
    afr[s] = a;
  }

  f32x4 acc[8];
#pragma unroll
  for (int t = 0; t < 8; ++t) acc[t] = (f32x4){0.f, 0.f, 0.f, 0.f};

#pragma unroll
  for (int s = 0; s < 4; ++s) {
#pragma unroll
    for (int t = 0; t < 8; ++t) {
      short8 b = *(const short8*)(Wb + ((size_t)(t * 16 + c) * 128 + 32 * s + 8 * g));
      acc[t] = __builtin_amdgcn_mfma_f32_16x16x32_bf16(afr[s], b, acc[t], 0, 0, 0);
    }
  }

  float wfs[8], wfd[8];
#pragma unroll
  for (int t = 0; t < 8; ++t) {
    wfs[t] = w_fc[t * 16 + c];
    wfd[t] = w_fc[128 + t * 16 + c];
  }

  const int rbase = m0 + 4 * g;
#pragma unroll
  for (int r = 0; r < 4; ++r) {
    const int row = rbase + r;
    if (row < n) {
#pragma unroll
      for (int tp = 0; tp < 4; ++tp) {
        unsigned dw = ((unsigned)f2bf(acc[tp + 4][r]) << 16) | (unsigned)f2bf(acc[tp][r]);
        zd[(size_t)row * 64 + tp * 16 + c] = dw;
      }
    }
    float ps = 0.f, pd = 0.f;
#pragma unroll
    for (int t = 0; t < 8; ++t) {
      ps += acc[t][r] * wfs[t];
      pd += acc[t][r] * wfd[t];
    }
#pragma unroll
    for (int off = 1; off < 16; off <<= 1) {
      ps += __shfl_xor(ps, off, 64);
      pd += __shfl_xor(pd, off, 64);
    }
    if (c == 0) {
      sfs[wid][4 * g + r] = ps;
      sfd[wid][4 * g + r] = pd;
    }
  }
  __syncthreads();

  const int nloc = lane >> 2;
  const int qc = lane & 3;
  const int node2 = m0 + nloc;
  float es = 0.f, ed = 0.f;
  if (node2 < n) {
    const float4* er = (const float4*)(emb + (size_t)node2 * 128 + qc * 32);
    const float4* wsp = (const float4*)(w_emb + qc * 32);
    const float4* wdp = (const float4*)(w_emb + 128 + qc * 32);
#pragma unroll
    for (int j = 0; j < 8; ++j) {
      float4 e4 = er[j], s4 = wsp[j], d4 = wdp[j];
      es += e4.x * s4.x + e4.y * s4.y + e4.z * s4.z + e4.w * s4.w;
      ed += e4.x * d4.x + e4.y * d4.y + e4.z * d4.z + e4.w * d4.w;
    }
  }
  es += __shfl_xor(es, 1, 64); es += __shfl_xor(es, 2, 64);
  ed += __shfl_xor(ed, 1, 64); ed += __shfl_xor(ed, 2, 64);
  if (qc == 0 && node2 < n) {
    a_src[node2] = es + sfs[wid][nloc];
    a_dst[node2] = ed + sfd[wid][nloc];
  }
}

// ---------------- K2: per-bin counting sort + ew -> packed 4B csr -------------
// in record = (src<<16) | dst ; out record = (src<<16) | f2bf(ew).
__global__ __launch_bounds__(256) void k_build(const unsigned* __restrict__ binrec,
                                               const int* __restrict__ bincur,
                                               const float* __restrict__ a_src,
                                               const float* __restrict__ a_dst,
                                               int2* __restrict__ row2,
                                               unsigned* __restrict__ csrp, int n) {
  __shared__ int hist[BDST], lrow[BDST], cur[BDST];
  __shared__ float adl[BDST];
  const int tid = threadIdx.x, b = blockIdx.x;
  const int cntb = bincur[b];
  const unsigned* rb = binrec + (size_t)b * CAPB;
  const int base = b * CAPB;

  if (tid < BDST) {
    hist[tid] = 0;
    int v = b * BDST + tid;
    adl[tid] = (v < n) ? a_dst[v] : 0.f;
  }
  __syncthreads();
  for (int i = tid; i < cntb; i += 256)
    atomicAdd(&hist[rb[i] & (BDST - 1)], 1);
  __syncthreads();
  if (tid < BDST) lrow[tid] = hist[tid];
  __syncthreads();
  for (int off = 1; off < BDST; off <<= 1) {
    int a = (tid < BDST && tid >= off) ? lrow[tid - off] : 0;
    __syncthreads();
    if (tid < BDST) lrow[tid] += a;
    __syncthreads();
  }
  if (tid < BDST) {
    int e = lrow[tid];
    int s = e - hist[tid];
    cur[tid] = s;
    int v = b * BDST + tid;
    if (v < n) row2[v] = make_int2(base + s, base + e);
  }
  __syncthreads();
  for (int i = tid; i < cntb; i += 256) {
    unsigned r = rb[i];
    int dl = r & (BDST - 1);
    unsigned sv = r >> 16;
    float a = a_src[sv] + adl[dl];
    float e = a > 0.f ? a : 0.01f * a;
    float ew = __expf(e);
    int pos = base + atomicAdd(&cur[dl], 1);
    csrp[pos] = (sv << 16) | (unsigned)f2bf(ew);
  }
}

// ---------------- K3: aggregation — packed 4B records, unroll 4 ---------------
__global__ __launch_bounds__(256) void k_agg(const unsigned* __restrict__ zd,
                                             const int2* __restrict__ row2,
                                             const unsigned* __restrict__ csrp,
                                             float* __restrict__ out, int n) {
  const int lane = threadIdx.x & 63;
  const int grp = lane >> 4;
  const int sub = lane & 15;
  const int v = blockIdx.x * 4 + (threadIdx.x >> 6);
  if (v >= n) return;
  const int2 be = row2[v];
  const int beg = be.x, end = be.y;

  f32x2 acc2[4];
#pragma unroll
  for (int j = 0; j < 4; ++j) acc2[j] = (f32x2){0.f, 0.f};
  float ews = 0.f;

#pragma unroll 4
  for (int i = beg + grp; i < end; i += 4) {
    const unsigned r = csrp[i];
    const float ew = __uint_as_float(r << 16);   // bf16 in low 16 -> f32
    const unsigned u = r >> 16;
    const uint4 zz = ((const uint4*)zd)[(size_t)u * 16 + sub];
    ews += ew;
    const f32x2 ew2 = {ew, ew};
    f32x2 z0 = {__uint_as_float(zz.x << 16), __uint_as_float(zz.x & 0xffff0000u)};
    f32x2 z1 = {__uint_as_float(zz.y << 16), __uint_as_float(zz.y & 0xffff0000u)};
    f32x2 z2 = {__uint_as_float(zz.z << 16), __uint_as_float(zz.z & 0xffff0000u)};
    f32x2 z3 = {__uint_as_float(zz.w << 16), __uint_as_float(zz.w & 0xffff0000u)};
    acc2[0] += ew2 * z0;
    acc2[1] += ew2 * z1;
    acc2[2] += ew2 * z2;
    acc2[3] += ew2 * z3;
  }

#pragma unroll
  for (int off = 16; off <= 32; off <<= 1) {
    ews += __shfl_xor(ews, off, 64);
#pragma unroll
    for (int j = 0; j < 4; ++j) {
      acc2[j][0] += __shfl_xor(acc2[j][0], off, 64);
      acc2[j][1] += __shfl_xor(acc2[j][1], off, 64);
    }
  }

  if (grp == 0) {
    const float inv = (end > beg) ? 1.f / ews : 0.f;
    float4 olo = make_float4(acc2[0][0] * inv, acc2[1][0] * inv, acc2[2][0] * inv, acc2[3][0] * inv);
    float4 ohi = make_float4(acc2[0][1] * inv, acc2[1][1] * inv, acc2[2][1] * inv, acc2[3][1] * inv);
    ((float4*)out)[(size_t)v * 32 + sub] = olo;
    ((float4*)out)[(size_t)v * 32 + 16 + sub] = ohi;
  }
}

extern "C" void kernel_launch(void* const* d_in, const int* in_sizes, int n_in,
                              void* d_out, int out_size, void* d_ws, size_t ws_size,
                              hipStream_t stream) {
  const float* h = (const float*)d_in[0];
  const float* emb = (const float*)d_in[1];
  const float* W = (const float*)d_in[2];
  const float* wfc = (const float*)d_in[3];
  const float* wemb = (const float*)d_in[4];
  const int* src = (const int*)d_in[5];
  const int* dst = (const int*)d_in[6];
  const int n = in_sizes[0] / D;
  const int E = in_sizes[5];
  const int NB = (n + BDST - 1) >> BSH;
  const int CHSZ = (E + NCHK - 1) / NCHK;
  const int NLIN = (n + 63) / 64;

  char* ws = (char*)d_ws;
  size_t off = 0;
  auto alloc = [&](size_t bytes) {
    void* p = ws + off;
    off = (off + bytes + 255) & ~(size_t)255;
    return p;
  };
  unsigned* zd = (unsigned*)alloc((size_t)n * 64 * 4);
  unsigned short* Wb = (unsigned short*)alloc(D * D * 2);
  float* a_src = (float*)alloc((size_t)n * 4);
  float* a_dst = (float*)alloc((size_t)n * 4);
  int* bincur = (int*)alloc((size_t)NB * 4);
  int2* row2 = (int2*)alloc((size_t)n * 8);
  unsigned* binrec = (unsigned*)alloc((size_t)NB * CAPB * 4);
  unsigned* csrp = (unsigned*)alloc((size_t)NB * CAPB * 4);
  (void)off;
  (void)ws_size;

  k_wconv<<<(D * D / 4 + 255) / 256, 256, 0, stream>>>(W, Wb, bincur, NB);
  k_combo<<<NCHK + NLIN, 256, 0, stream>>>(h, Wb, wfc, emb, wemb, zd, a_src, a_dst,
                                           src, dst, bincur, binrec, n, E, NB, CHSZ);
  k_build<<<NB, 256, 0, stream>>>(binrec, bincur, a_src, a_dst, row2, csrp, n);
  k_agg<<<(n + 3) / 4, 256, 0, stream>>>(zd, row2, csrp, (float*)d_out, n);
}